// Round 3
// baseline (5255.948 us; speedup 1.0000x reference)
//
#include <hip/hip_runtime.h>

#define KCODES 16384
#define CDIM   32
#define NROWS  8192
#define RPB    32                 // rows per block
#define KT     256                // codes per K-tile
#define KSPLIT 4                  // K-chunks
#define CHUNK  (KCODES/KSPLIT)    // 4096
#define TILES  (CHUNK/KT)         // 16
#define CUT    -35.0f             // exp cutoff: exp(-35)=6e-16, invisible vs +1e-5 in logs

// workspace layout (floats)
#define WS_MSE   0
#define WS_PLP   1
#define WS_AVGP  16
#define WS_ENORM (16 + KCODES)
#define WS_LSE   (16 + 2*KCODES)
#define WS_PART  (16 + 2*KCODES + NROWS)   // 16B-aligned float4 region

// output layout (floats): z_q [0, N*C), loss [N*C], idx [N*C+1, ...)
#define OUT_LOSS (NROWS*CDIM)
#define OUT_IDX  (NROWS*CDIM + 1)

__global__ __launch_bounds__(256) void prep_kernel(const float* __restrict__ emb,
                                                   float* __restrict__ ws) {
  int k = blockIdx.x * 256 + threadIdx.x;
  const float4* p = (const float4*)(emb + (size_t)k * CDIM);
  float s = 0.f;
#pragma unroll
  for (int i = 0; i < 8; ++i) {
    float4 v = p[i];
    s += v.x*v.x + v.y*v.y + v.z*v.z + v.w*v.w;
  }
  ws[WS_ENORM + k] = s;
}

// ---------------------------------------------------------------------------
// pass1_part: block = (rowgroup, chunk). 32 rows x 4096 codes.
// Thread tile: 8 rows x 4 codes; codes split in two 128-halves across waves.
// Tracks (m, s, imin) per row; partial written to ws_part[chunk][row].
// ---------------------------------------------------------------------------
__global__ __launch_bounds__(256, 3) void pass1_part(const float* __restrict__ z,
                                                     const float* __restrict__ emb,
                                                     const float* __restrict__ ws,
                                                     float4* __restrict__ part) {
  __shared__ float  zs[RPB][36];      // 16B-aligned rows
  __shared__ float  znorm_s[RPB];
  __shared__ float4 es4[KT][9];       // pad slot -> measured conflict-free
  __shared__ float  es_n[KT];
  __shared__ float  red_m[RPB][2];
  __shared__ float  red_s[RPB][2];
  __shared__ int    red_i[RPB][2];

  const int tid   = threadIdx.x;
  const int n0    = blockIdx.x * RPB;
  const int kbase = blockIdx.y * CHUNK;
  const int b     = n0 >> 8;
  const int hw0   = n0 & 255;

  { // stage z tile: 32 rows x 32 ch
    int c  = tid >> 3;
    int i0 = (tid & 7) * 4;
    const float4 v = *(const float4*)(z + (size_t)b*8192 + c*256 + hw0 + i0);
    zs[i0+0][c] = v.x; zs[i0+1][c] = v.y; zs[i0+2][c] = v.z; zs[i0+3][c] = v.w;
  }
  __syncthreads();
  if (tid < RPB) {
    float t = 0.f;
#pragma unroll
    for (int c = 0; c < CDIM; ++c) t += zs[tid][c]*zs[tid][c];
    znorm_s[tid] = t;
  }
  __syncthreads();

  const int hi    = tid >> 7;         // code half 0/1
  const int rg    = (tid >> 5) & 3;   // rows rg*8 .. rg*8+7
  const int cg    = tid & 31;
  const int cbase = cg + 128*hi;      // code = cbase + 32*j

  float zn[8];
#pragma unroll
  for (int r = 0; r < 8; ++r) zn[r] = znorm_s[rg*8 + r];

  float m[8], s[8];
  int   imin[8];
#pragma unroll
  for (int r = 0; r < 8; ++r) { m[r] = -3.0e38f; s[r] = 0.f; imin[r] = kbase; }

  const float4* emb4  = (const float4*)emb;
  const float*  enorm = ws + WS_ENORM;

  for (int t = 0; t < TILES; ++t) {
    const int k0 = kbase + t*KT;
#pragma unroll
    for (int w = 0; w < 8; ++w) {     // 2048 float4 / 256 threads, coalesced
      int g = tid + 256*w;
      es4[g>>3][g&7] = emb4[(size_t)(k0 + (g>>3))*8 + (g&7)];
    }
    es_n[tid] = enorm[k0 + tid];
    __syncthreads();

    float acc[8][4];
#pragma unroll
    for (int r = 0; r < 8; ++r)
#pragma unroll
      for (int j = 0; j < 4; ++j) acc[r][j] = 0.f;

#pragma unroll
    for (int c4 = 0; c4 < 8; ++c4) {
      float4 zv[8];
#pragma unroll
      for (int r = 0; r < 8; ++r) zv[r] = *(const float4*)(&zs[rg*8 + r][c4*4]);
#pragma unroll
      for (int j = 0; j < 4; ++j) {
        float4 ev = es4[cbase + 32*j][c4];
#pragma unroll
        for (int r = 0; r < 8; ++r) {
          acc[r][j] = fmaf(zv[r].x, ev.x, acc[r][j]);
          acc[r][j] = fmaf(zv[r].y, ev.y, acc[r][j]);
          acc[r][j] = fmaf(zv[r].z, ev.z, acc[r][j]);
          acc[r][j] = fmaf(zv[r].w, ev.w, acc[r][j]);
        }
      }
    }

    float en[4];
#pragma unroll
    for (int j = 0; j < 4; ++j) en[j] = es_n[cbase + 32*j];

#pragma unroll
    for (int r = 0; r < 8; ++r) {
      float l[4];
#pragma unroll
      for (int j = 0; j < 4; ++j) {
        float v = fmaf(-2.f, acc[r][j], zn[r] + en[j]);   // same bits as round 2
        l[j] = -100.f * v;
      }
      float lm = fmaxf(fmaxf(l[0], l[1]), fmaxf(l[2], l[3]));
      if (lm > m[r] + CUT) {            // rare: tile contributes to this row
        if (lm > m[r]) {                // new min distance
          int jstar = 3;
          if (l[2] == lm) jstar = 2;    // first j achieving max (ascending code)
          if (l[1] == lm) jstar = 1;
          if (l[0] == lm) jstar = 0;
          imin[r] = k0 + cbase + 32*jstar;
          s[r] *= __expf(m[r] - lm);
          m[r]  = lm;
        }
#pragma unroll
        for (int j = 0; j < 4; ++j) {
          float u = l[j] - m[r];
          if (u > CUT) s[r] += __expf(u);
        }
      }
    }
    __syncthreads();
  }

  // reduce (m,s,imin) across the 32 cg lanes (stays within 32-lane halves)
#pragma unroll
  for (int r = 0; r < 8; ++r) {
    float mm = m[r], ss = s[r];
    int   ii = imin[r];
    for (int off = 1; off < 32; off <<= 1) {
      float mo = __shfl_xor(mm, off);
      float so = __shfl_xor(ss, off);
      int   io = __shfl_xor(ii, off);
      float M  = fmaxf(mm, mo);
      ss = ss*__expf(mm - M) + so*__expf(mo - M);
      ii = (mo > mm || (mo == mm && io < ii)) ? io : ii;
      mm = M;
    }
    if (cg == 0) {
      int row = rg*8 + r;
      red_m[row][hi] = mm; red_s[row][hi] = ss; red_i[row][hi] = ii;
    }
  }
  __syncthreads();

  if (tid < RPB) {  // merge the two code halves; hi=0 has lower indices
    float m0 = red_m[tid][0], s0 = red_s[tid][0];
    float m1 = red_m[tid][1], s1 = red_s[tid][1];
    int   i0 = red_i[tid][0], i1 = red_i[tid][1];
    float M  = fmaxf(m0, m1);
    float ss = s0*__expf(m0 - M) + s1*__expf(m1 - M);
    int   ii = (m1 > m0) ? i1 : i0;
    part[(size_t)blockIdx.y*NROWS + n0 + tid] = make_float4(M, ss, 0.f, __int_as_float(ii));
  }
}

// ---------------------------------------------------------------------------
// combine: merge KSPLIT partials per row -> lse, idx
// ---------------------------------------------------------------------------
__global__ __launch_bounds__(256) void combine_kernel(const float4* __restrict__ part,
                                                      float* __restrict__ ws,
                                                      float* __restrict__ out) {
  int n = blockIdx.x*256 + threadIdx.x;
  float4 p0 = part[n];
  float mm = p0.x, ss = p0.y;
  int   ii = __float_as_int(p0.w);
#pragma unroll
  for (int c = 1; c < KSPLIT; ++c) {
    float4 pc = part[(size_t)c*NROWS + n];
    float M = fmaxf(mm, pc.x);
    ss = ss*__expf(mm - M) + pc.y*__expf(pc.x - M);
    if (pc.x > mm) ii = __float_as_int(pc.w);   // ties keep earlier chunk
    mm = M;
  }
  ws[WS_LSE + n] = mm + __logf(ss);
  out[OUT_IDX + n] = (float)ii;
}

// ---------------------------------------------------------------------------
// zq epilogue: straight-through output + MSE
// ---------------------------------------------------------------------------
__global__ __launch_bounds__(256) void zq_kernel(const float* __restrict__ z,
                                                 const float* __restrict__ emb,
                                                 float* __restrict__ ws,
                                                 float* __restrict__ out) {
  int f  = blockIdx.x*256 + threadIdx.x;   // f = b*8192 + c*256 + hw
  int hw = f & 255;
  int c  = (f >> 8) & 31;
  int b  = f >> 13;
  int n  = b*256 + hw;
  int idx = (int)out[OUT_IDX + n];
  float zq = emb[(size_t)idx*CDIM + c];
  float zf = z[f];
  out[f] = zf + (zq - zf);
  float d = zq - zf;
  float msel = d*d;
  for (int off = 1; off < 64; off <<= 1) msel += __shfl_xor(msel, off);
  if ((threadIdx.x & 63) == 0) atomicAdd(&ws[WS_MSE], msel);
}

// ---------------------------------------------------------------------------
// pass2_part: recompute logits, p = exp(l - lse); accumulate avg_probs (rare
// direct atomics) and sum p*(l-lse) for sample entropy.
// ---------------------------------------------------------------------------
__global__ __launch_bounds__(256, 3) void pass2_part(const float* __restrict__ z,
                                                     const float* __restrict__ emb,
                                                     float* __restrict__ ws) {
  __shared__ float  zs[RPB][36];
  __shared__ float  znorm_s[RPB];
  __shared__ float4 es4[KT][9];
  __shared__ float  es_n[KT];

  const int tid   = threadIdx.x;
  const int n0    = blockIdx.x * RPB;
  const int kbase = blockIdx.y * CHUNK;
  const int b     = n0 >> 8;
  const int hw0   = n0 & 255;

  {
    int c  = tid >> 3;
    int i0 = (tid & 7) * 4;
    const float4 v = *(const float4*)(z + (size_t)b*8192 + c*256 + hw0 + i0);
    zs[i0+0][c] = v.x; zs[i0+1][c] = v.y; zs[i0+2][c] = v.z; zs[i0+3][c] = v.w;
  }
  __syncthreads();
  if (tid < RPB) {
    float t = 0.f;
#pragma unroll
    for (int c = 0; c < CDIM; ++c) t += zs[tid][c]*zs[tid][c];
    znorm_s[tid] = t;
  }
  __syncthreads();

  const int hi    = tid >> 7;
  const int rg    = (tid >> 5) & 3;
  const int cg    = tid & 31;
  const int cbase = cg + 128*hi;

  float zn[8], lse_r[8];
#pragma unroll
  for (int r = 0; r < 8; ++r) {
    zn[r]    = znorm_s[rg*8 + r];
    lse_r[r] = ws[WS_LSE + n0 + rg*8 + r];
  }

  const float4* emb4  = (const float4*)emb;
  const float*  enorm = ws + WS_ENORM;
  float plp = 0.f;

  for (int t = 0; t < TILES; ++t) {
    const int k0 = kbase + t*KT;
#pragma unroll
    for (int w = 0; w < 8; ++w) {
      int g = tid + 256*w;
      es4[g>>3][g&7] = emb4[(size_t)(k0 + (g>>3))*8 + (g&7)];
    }
    es_n[tid] = enorm[k0 + tid];
    __syncthreads();

    float acc[8][4];
#pragma unroll
    for (int r = 0; r < 8; ++r)
#pragma unroll
      for (int j = 0; j < 4; ++j) acc[r][j] = 0.f;

#pragma unroll
    for (int c4 = 0; c4 < 8; ++c4) {
      float4 zv[8];
#pragma unroll
      for (int r = 0; r < 8; ++r) zv[r] = *(const float4*)(&zs[rg*8 + r][c4*4]);
#pragma unroll
      for (int j = 0; j < 4; ++j) {
        float4 ev = es4[cbase + 32*j][c4];
#pragma unroll
        for (int r = 0; r < 8; ++r) {
          acc[r][j] = fmaf(zv[r].x, ev.x, acc[r][j]);
          acc[r][j] = fmaf(zv[r].y, ev.y, acc[r][j]);
          acc[r][j] = fmaf(zv[r].z, ev.z, acc[r][j]);
          acc[r][j] = fmaf(zv[r].w, ev.w, acc[r][j]);
        }
      }
    }

    float en[4];
#pragma unroll
    for (int j = 0; j < 4; ++j) en[j] = es_n[cbase + 32*j];

    float a4[4] = {0.f, 0.f, 0.f, 0.f};
#pragma unroll
    for (int r = 0; r < 8; ++r) {
      float l[4];
#pragma unroll
      for (int j = 0; j < 4; ++j) {
        float v = fmaf(-2.f, acc[r][j], zn[r] + en[j]);
        l[j] = -100.f * v;
      }
      float lm = fmaxf(fmaxf(l[0], l[1]), fmaxf(l[2], l[3]));
      if (lm - lse_r[r] > CUT) {        // rare
#pragma unroll
        for (int j = 0; j < 4; ++j) {
          float u = l[j] - lse_r[r];
          if (u > CUT) {
            float p = __expf(u);
            a4[j] += p;
            plp = fmaf(p, u, plp);
          }
        }
      }
    }
#pragma unroll
    for (int j = 0; j < 4; ++j)
      if (a4[j] != 0.f) atomicAdd(&ws[WS_AVGP + k0 + cbase + 32*j], a4[j]);
    __syncthreads();
  }

  for (int off = 1; off < 64; off <<= 1) plp += __shfl_xor(plp, off);
  if ((tid & 63) == 0) atomicAdd(&ws[WS_PLP], plp);
}

__global__ __launch_bounds__(256) void finalize_kernel(const float* __restrict__ ws,
                                                       float* __restrict__ out) {
  __shared__ float red[256];
  float h = 0.f;
  for (int k = threadIdx.x; k < KCODES; k += 256) {
    float ap = ws[WS_AVGP + k] * (1.f/8192.f);
    h += ap * __logf(ap + 1e-5f);
  }
  red[threadIdx.x] = h;
  __syncthreads();
  for (int st = 128; st > 0; st >>= 1) {
    if (threadIdx.x < st) red[threadIdx.x] += red[threadIdx.x + st];
    __syncthreads();
  }
  if (threadIdx.x == 0) {
    float mse        = ws[WS_MSE] * (1.f/(8192.f*32.f));
    float sample_ent = -ws[WS_PLP] * (1.f/8192.f);
    out[OUT_LOSS] = 1.25f*mse + 0.1f*(sample_ent + red[0]);
  }
}

extern "C" void kernel_launch(void* const* d_in, const int* in_sizes, int n_in,
                              void* d_out, int out_size, void* d_ws, size_t ws_size,
                              hipStream_t stream) {
  (void)in_sizes; (void)n_in; (void)out_size; (void)ws_size;
  const float* z   = (const float*)d_in[0];
  const float* emb = (const float*)d_in[1];
  float* out = (float*)d_out;
  float* ws  = (float*)d_ws;
  float4* part = (float4*)(ws + WS_PART);

  hipMemsetAsync(ws, 0, (size_t)(16 + KCODES)*sizeof(float), stream);

  prep_kernel    <<<KCODES/256, 256, 0, stream>>>(emb, ws);
  pass1_part     <<<dim3(NROWS/RPB, KSPLIT), 256, 0, stream>>>(z, emb, ws, part);
  combine_kernel <<<NROWS/256, 256, 0, stream>>>(part, ws, out);
  zq_kernel      <<<(NROWS*CDIM)/256, 256, 0, stream>>>(z, emb, ws, out);
  pass2_part     <<<dim3(NROWS/RPB, KSPLIT), 256, 0, stream>>>(z, emb, ws);
  finalize_kernel<<<1, 256, 0, stream>>>(ws, out);
}

// Round 5
// 3945.204 us; speedup vs baseline: 1.3322x; 1.3322x over previous
//
#include <hip/hip_runtime.h>

#define KCODES 16384
#define CDIM   32
#define NROWS  8192
#define RPB    32                 // rows per block
#define KT     256                // codes per K-tile
#define KSPLIT 4                  // K-chunks
#define CHUNK  (KCODES/KSPLIT)    // 4096
#define TILES  (CHUNK/KT)         // 16
#define CUT    -18.0f             // exp(-18)=1.5e-8 << 1e-5 log-offsets -> invisible in loss
#define SLOTS  48                 // candidate slots per row (expected ~10 at CUT=-18)

// workspace layout (float indices) — identical footprint to round 4 (proven in-bounds)
#define WS_MSE   0
#define WS_PLP   1
#define WS_AVGP  16                       // [16384]
#define WS_CNT   (16 + KCODES)            // [8192] ints
#define WS_ENORM (16 + KCODES + NROWS)    // [16384]
#define WS_PART  (WS_ENORM + KCODES)      // float2[KSPLIT][NROWS]
#define WS_CAND  (WS_PART + 2*KSPLIT*NROWS) // float2[NROWS][SLOTS]

// output layout (floats): z_q [0, N*C), loss [N*C], idx [N*C+1, ...)
#define OUT_LOSS (NROWS*CDIM)
#define OUT_IDX  (NROWS*CDIM + 1)

__global__ __launch_bounds__(256) void prep_kernel(const float* __restrict__ emb,
                                                   float* __restrict__ ws) {
  int k = blockIdx.x * 256 + threadIdx.x;
  const float4* p = (const float4*)(emb + (size_t)k * CDIM);
  float s = 0.f;
#pragma unroll
  for (int i = 0; i < 8; ++i) {
    float4 v = p[i];
    s += v.x*v.x + v.y*v.y + v.z*v.z + v.w*v.w;
  }
  ws[WS_ENORM + k] = s;
}

// ---------------------------------------------------------------------------
// pass1: block = (rowgroup, chunk). 32 rows x 4096 codes, 4 rows x 8 codes per
// thread (round-2 proven shape). Emits (rowmax, argmin) partial per chunk and
// candidate (l, code) pairs with l > rowmax-18. No exp in the hot loop.
// ---------------------------------------------------------------------------
__global__ __launch_bounds__(256, 3) void pass1_part(const float* __restrict__ z,
                                                     const float* __restrict__ emb,
                                                     float* __restrict__ ws) {
  __shared__ float  zs[RPB][36];      // 16B-aligned rows, broadcast reads
  __shared__ float  znorm_s[RPB];
  __shared__ float4 es4[KT][9];       // pad slot -> conflict-free b128 reads
  __shared__ float  es_n[KT];

  const int tid   = threadIdx.x;
  const int n0    = blockIdx.x * RPB;
  const int kbase = blockIdx.y * CHUNK;
  const int b     = n0 >> 8;
  const int hw0   = n0 & 255;

  int*    cnt  = ((int*)ws) + WS_CNT;
  float2* cand = (float2*)(ws + WS_CAND);
  float2* part = (float2*)(ws + WS_PART);

  { // stage z tile: 32 rows x 32 ch
    int c  = tid >> 3;
    int i0 = (tid & 7) * 4;
    const float4 v = *(const float4*)(z + (size_t)b*8192 + c*256 + hw0 + i0);
    zs[i0+0][c] = v.x; zs[i0+1][c] = v.y; zs[i0+2][c] = v.z; zs[i0+3][c] = v.w;
  }
  __syncthreads();
  if (tid < RPB) {
    float t = 0.f;
#pragma unroll
    for (int c = 0; c < CDIM; ++c) t += zs[tid][c]*zs[tid][c];
    znorm_s[tid] = t;
  }
  __syncthreads();

  const int rg = tid >> 5;            // rows rg*4 .. rg*4+3
  const int cg = tid & 31;            // codes cg + 32*j

  float zn[4];
#pragma unroll
  for (int r = 0; r < 4; ++r) zn[r] = znorm_s[rg*4 + r];

  float m_thr[4], m_row[4];
  int   imin[4];
#pragma unroll
  for (int r = 0; r < 4; ++r) { m_thr[r] = -3.0e38f; m_row[r] = -3.0e38f; imin[r] = kbase; }

  const float4* emb4  = (const float4*)emb;
  const float*  enorm = ws + WS_ENORM;

  for (int t = 0; t < TILES; ++t) {
    const int k0 = kbase + t*KT;
#pragma unroll
    for (int w = 0; w < 8; ++w) {     // 2048 float4 / 256 threads, coalesced
      int g = tid + 256*w;
      es4[g>>3][g&7] = emb4[(size_t)(k0 + (g>>3))*8 + (g&7)];
    }
    es_n[tid] = enorm[k0 + tid];
    __syncthreads();

    float acc[4][8];
#pragma unroll
    for (int r = 0; r < 4; ++r)
#pragma unroll
      for (int j = 0; j < 8; ++j) acc[r][j] = 0.f;

#pragma unroll
    for (int c4 = 0; c4 < 8; ++c4) {
      float4 zv[4];
#pragma unroll
      for (int r = 0; r < 4; ++r) zv[r] = *(const float4*)(&zs[rg*4 + r][c4*4]);
#pragma unroll
      for (int j = 0; j < 8; ++j) {
        float4 ev = es4[cg + 32*j][c4];
#pragma unroll
        for (int r = 0; r < 4; ++r) {
          acc[r][j] = fmaf(zv[r].x, ev.x, acc[r][j]);
          acc[r][j] = fmaf(zv[r].y, ev.y, acc[r][j]);
          acc[r][j] = fmaf(zv[r].z, ev.z, acc[r][j]);
          acc[r][j] = fmaf(zv[r].w, ev.w, acc[r][j]);
        }
      }
    }

    float en[8];
#pragma unroll
    for (int j = 0; j < 8; ++j) en[j] = es_n[cg + 32*j];

#pragma unroll
    for (int r = 0; r < 4; ++r) {
      float l[8];
#pragma unroll
      for (int j = 0; j < 8; ++j)
        l[j] = -100.f * fmaf(-2.f, acc[r][j], zn[r] + en[j]);   // same bits as R2

      float lm = l[0];
#pragma unroll
      for (int j = 1; j < 8; ++j) lm = fmaxf(lm, l[j]);

      // per-thread argmin (first-j on ties -> lowest code)
      if (lm > m_thr[r]) {
        int jstar = 7;
#pragma unroll
        for (int j = 6; j >= 0; --j) if (l[j] == lm) jstar = j;
        imin[r]  = k0 + cg + 32*jstar;
        m_thr[r] = lm;
      }

      // wave-shared running row max (tight candidate filter)
      float lmr = lm;
      for (int off = 1; off < 32; off <<= 1) lmr = fmaxf(lmr, __shfl_xor(lmr, off));
      float M = fmaxf(m_row[r], lmr);
      m_row[r] = M;

      if (lm > M + CUT) {             // rare
        int row = n0 + rg*4 + r;
#pragma unroll
        for (int j = 0; j < 8; ++j) {
          if (l[j] > M + CUT) {
            int slot = atomicAdd(&cnt[row], 1);
            if (slot < SLOTS)
              cand[(size_t)row*SLOTS + slot] =
                  make_float2(l[j], __int_as_float(k0 + cg + 32*j));
          }
        }
      }
    }
    __syncthreads();
  }

  // reduce (m_thr, imin) across the 32 cg lanes
#pragma unroll
  for (int r = 0; r < 4; ++r) {
    float mm = m_thr[r];
    int   ii = imin[r];
    for (int off = 1; off < 32; off <<= 1) {
      float mo = __shfl_xor(mm, off);
      int   io = __shfl_xor(ii, off);
      ii = (mo > mm || (mo == mm && io < ii)) ? io : ii;
      mm = fmaxf(mm, mo);
    }
    if (cg == 0)
      part[(size_t)blockIdx.y*NROWS + n0 + rg*4 + r] = make_float2(mm, __int_as_float(ii));
  }
}

// ---------------------------------------------------------------------------
// combine: merge chunk maxima -> idx; softmax stats from candidates.
// NaN-proof: the argmax term (l == mm bit-exact) is added explicitly, and any
// candidate with code == argmin is skipped -> s >= 1, p <= 1 always.
// ---------------------------------------------------------------------------
__global__ __launch_bounds__(256) void combine_kernel(float* __restrict__ ws,
                                                      float* __restrict__ out) {
  const float2* part = (const float2*)(ws + WS_PART);
  const float2* cand = (const float2*)(ws + WS_CAND);
  const int*    cnt  = ((const int*)ws) + WS_CNT;

  int n = blockIdx.x*256 + threadIdx.x;
  float2 p0 = part[n];
  float mm = p0.x;
  int   ii = __float_as_int(p0.y);
#pragma unroll
  for (int c = 1; c < KSPLIT; ++c) {
    float2 pc = part[(size_t)c*NROWS + n];
    if (pc.x > mm) { mm = pc.x; ii = __float_as_int(pc.y); }  // ties keep earlier chunk
  }
  out[OUT_IDX + n] = (float)ii;

  int cn = cnt[n]; cn = cn < SLOTS ? cn : SLOTS;
  float s = 1.f;                       // argmax term: exp(mm - mm) == 1 exactly
  for (int i = 0; i < cn; ++i) {
    float2 cd = cand[(size_t)n*SLOTS + i];
    if (__float_as_int(cd.y) != ii) s += __expf(cd.x - mm);
  }
  float lse = mm + __logf(s);          // s >= 1 -> finite, lse >= mm

  float um   = mm - lse;               // <= 0
  float pmax = __expf(um);
  float plp  = pmax * um;
  atomicAdd(&ws[WS_AVGP + ii], pmax);
  for (int i = 0; i < cn; ++i) {
    float2 cd = cand[(size_t)n*SLOTS + i];
    if (__float_as_int(cd.y) == ii) continue;
    float u = cd.x - lse;              // <= 0
    float p = __expf(u);
    plp = fmaf(p, u, plp);
    atomicAdd(&ws[WS_AVGP + __float_as_int(cd.y)], p);
  }
  for (int off = 1; off < 64; off <<= 1) plp += __shfl_xor(plp, off);
  if ((threadIdx.x & 63) == 0) atomicAdd(&ws[WS_PLP], plp);
}

// ---------------------------------------------------------------------------
// zq epilogue: straight-through output + MSE
// ---------------------------------------------------------------------------
__global__ __launch_bounds__(256) void zq_kernel(const float* __restrict__ z,
                                                 const float* __restrict__ emb,
                                                 float* __restrict__ ws,
                                                 float* __restrict__ out) {
  int f  = blockIdx.x*256 + threadIdx.x;   // f = b*8192 + c*256 + hw
  int hw = f & 255;
  int c  = (f >> 8) & 31;
  int b  = f >> 13;
  int n  = b*256 + hw;
  int idx = (int)out[OUT_IDX + n];
  float zq = emb[(size_t)idx*CDIM + c];
  float zf = z[f];
  out[f] = zf + (zq - zf);
  float d = zq - zf;
  float msel = d*d;
  for (int off = 1; off < 64; off <<= 1) msel += __shfl_xor(msel, off);
  if ((threadIdx.x & 63) == 0) atomicAdd(&ws[WS_MSE], msel);
}

__global__ __launch_bounds__(256) void finalize_kernel(const float* __restrict__ ws,
                                                       float* __restrict__ out) {
  __shared__ float red[256];
  float h = 0.f;
  for (int k = threadIdx.x; k < KCODES; k += 256) {
    float ap = ws[WS_AVGP + k] * (1.f/8192.f);
    h += ap * __logf(ap + 1e-5f);
  }
  red[threadIdx.x] = h;
  __syncthreads();
  for (int st = 128; st > 0; st >>= 1) {
    if (threadIdx.x < st) red[threadIdx.x] += red[threadIdx.x + st];
    __syncthreads();
  }
  if (threadIdx.x == 0) {
    float mse        = ws[WS_MSE] * (1.f/(8192.f*32.f));
    float sample_ent = -ws[WS_PLP] * (1.f/8192.f);
    out[OUT_LOSS] = 1.25f*mse + 0.1f*(sample_ent + red[0]);
  }
}

extern "C" void kernel_launch(void* const* d_in, const int* in_sizes, int n_in,
                              void* d_out, int out_size, void* d_ws, size_t ws_size,
                              hipStream_t stream) {
  (void)in_sizes; (void)n_in; (void)out_size; (void)ws_size;
  const float* z   = (const float*)d_in[0];
  const float* emb = (const float*)d_in[1];
  float* out = (float*)d_out;
  float* ws  = (float*)d_ws;

  // zero scalars + avg_probs + candidate counters
  hipMemsetAsync(ws, 0, (size_t)(16 + KCODES + NROWS)*sizeof(float), stream);

  prep_kernel    <<<KCODES/256, 256, 0, stream>>>(emb, ws);
  pass1_part     <<<dim3(NROWS/RPB, KSPLIT), 256, 0, stream>>>(z, emb, ws);
  combine_kernel <<<NROWS/256, 256, 0, stream>>>(ws, out);
  zq_kernel      <<<(NROWS*CDIM)/256, 256, 0, stream>>>(z, emb, ws, out);
  finalize_kernel<<<1, 256, 0, stream>>>(ws, out);
}

// Round 6
// 773.065 us; speedup vs baseline: 6.7988x; 5.1033x over previous
//
#include <hip/hip_runtime.h>

#define KCODES 16384
#define CDIM   32
#define NROWS  8192
#define RPB    32                 // rows per block
#define KT     256                // codes per K-tile
#define KSPLIT 4                  // K-chunks
#define CHUNK  (KCODES/KSPLIT)    // 4096
#define TILES  (CHUNK/KT)         // 16
#define CUT    -18.0f             // exp(-18)=1.5e-8 << 1e-5 log-offsets -> invisible in loss
#define SLOTS  48                 // candidate slots per row (expected ~10 at CUT=-18)

// workspace layout (float indices) — identical footprint to round 4/5 (proven in-bounds)
#define WS_MSE   0
#define WS_PLP   1
#define WS_AVGP  16                       // [16384]
#define WS_CNT   (16 + KCODES)            // [8192] ints
#define WS_ENORM (16 + KCODES + NROWS)    // [16384]
#define WS_PART  (WS_ENORM + KCODES)      // float2[KSPLIT][NROWS]
#define WS_CAND  (WS_PART + 2*KSPLIT*NROWS) // float2[NROWS][SLOTS]

// output layout (floats): z_q [0, N*C), loss [N*C], idx [N*C+1, ...)
#define OUT_LOSS (NROWS*CDIM)
#define OUT_IDX  (NROWS*CDIM + 1)

__global__ __launch_bounds__(256) void prep_kernel(const float* __restrict__ emb,
                                                   float* __restrict__ ws) {
  int k = blockIdx.x * 256 + threadIdx.x;
  const float4* p = (const float4*)(emb + (size_t)k * CDIM);
  float s = 0.f;
#pragma unroll
  for (int i = 0; i < 8; ++i) {
    float4 v = p[i];
    s += v.x*v.x + v.y*v.y + v.z*v.z + v.w*v.w;
  }
  ws[WS_ENORM + k] = s;
}

// ---------------------------------------------------------------------------
// pass1: block = (rowgroup, chunk). 32 rows x 4096 codes, 4 rows x 8 codes per
// thread. NO __launch_bounds__ min-waves: (256,3) forces the <=128-VGPR tier
// and spills the accumulators to scratch (R3/R5: VGPR=84, GBs of FETCH, 9x
// slowdown). Unbounded build (R2): 220 VGPR, no spill, 450 us.
// ---------------------------------------------------------------------------
__global__ __launch_bounds__(256) void pass1_part(const float* __restrict__ z,
                                                  const float* __restrict__ emb,
                                                  float* __restrict__ ws) {
  __shared__ float  zs[RPB][36];      // 16B-aligned rows, broadcast reads
  __shared__ float  znorm_s[RPB];
  __shared__ float4 es4[KT][9];       // pad slot -> conflict-free b128 reads
  __shared__ float  es_n[KT];

  const int tid   = threadIdx.x;
  const int n0    = blockIdx.x * RPB;
  const int kbase = blockIdx.y * CHUNK;
  const int b     = n0 >> 8;
  const int hw0   = n0 & 255;

  int*    cnt  = ((int*)ws) + WS_CNT;
  float2* cand = (float2*)(ws + WS_CAND);
  float2* part = (float2*)(ws + WS_PART);

  { // stage z tile: 32 rows x 32 ch
    int c  = tid >> 3;
    int i0 = (tid & 7) * 4;
    const float4 v = *(const float4*)(z + (size_t)b*8192 + c*256 + hw0 + i0);
    zs[i0+0][c] = v.x; zs[i0+1][c] = v.y; zs[i0+2][c] = v.z; zs[i0+3][c] = v.w;
  }
  __syncthreads();
  if (tid < RPB) {
    float t = 0.f;
#pragma unroll
    for (int c = 0; c < CDIM; ++c) t += zs[tid][c]*zs[tid][c];
    znorm_s[tid] = t;
  }
  __syncthreads();

  const int rg = tid >> 5;            // rows rg*4 .. rg*4+3
  const int cg = tid & 31;            // codes cg + 32*j

  float zn[4];
#pragma unroll
  for (int r = 0; r < 4; ++r) zn[r] = znorm_s[rg*4 + r];

  float m_thr[4], m_row[4];
  int   imin[4];
#pragma unroll
  for (int r = 0; r < 4; ++r) { m_thr[r] = -3.0e38f; m_row[r] = -3.0e38f; imin[r] = kbase; }

  const float4* emb4  = (const float4*)emb;
  const float*  enorm = ws + WS_ENORM;

  for (int t = 0; t < TILES; ++t) {
    const int k0 = kbase + t*KT;
#pragma unroll
    for (int w = 0; w < 8; ++w) {     // 2048 float4 / 256 threads, coalesced
      int g = tid + 256*w;
      es4[g>>3][g&7] = emb4[(size_t)(k0 + (g>>3))*8 + (g&7)];
    }
    es_n[tid] = enorm[k0 + tid];
    __syncthreads();

    float acc[4][8];
#pragma unroll
    for (int r = 0; r < 4; ++r)
#pragma unroll
      for (int j = 0; j < 8; ++j) acc[r][j] = 0.f;

#pragma unroll
    for (int c4 = 0; c4 < 8; ++c4) {
      float4 zv[4];
#pragma unroll
      for (int r = 0; r < 4; ++r) zv[r] = *(const float4*)(&zs[rg*4 + r][c4*4]);
#pragma unroll
      for (int j = 0; j < 8; ++j) {
        float4 ev = es4[cg + 32*j][c4];
#pragma unroll
        for (int r = 0; r < 4; ++r) {
          acc[r][j] = fmaf(zv[r].x, ev.x, acc[r][j]);
          acc[r][j] = fmaf(zv[r].y, ev.y, acc[r][j]);
          acc[r][j] = fmaf(zv[r].z, ev.z, acc[r][j]);
          acc[r][j] = fmaf(zv[r].w, ev.w, acc[r][j]);
        }
      }
    }

    float en[8];
#pragma unroll
    for (int j = 0; j < 8; ++j) en[j] = es_n[cg + 32*j];

#pragma unroll
    for (int r = 0; r < 4; ++r) {
      float l[8];
#pragma unroll
      for (int j = 0; j < 8; ++j)
        l[j] = -100.f * fmaf(-2.f, acc[r][j], zn[r] + en[j]);   // same bits as R2

      float lm = l[0];
#pragma unroll
      for (int j = 1; j < 8; ++j) lm = fmaxf(lm, l[j]);

      // per-thread argmin (first-j on ties -> lowest code)
      if (lm > m_thr[r]) {
        int jstar = 7;
#pragma unroll
        for (int j = 6; j >= 0; --j) if (l[j] == lm) jstar = j;
        imin[r]  = k0 + cg + 32*jstar;
        m_thr[r] = lm;
      }

      // wave-shared running row max (tight candidate filter)
      float lmr = lm;
      for (int off = 1; off < 32; off <<= 1) lmr = fmaxf(lmr, __shfl_xor(lmr, off));
      float M = fmaxf(m_row[r], lmr);
      m_row[r] = M;

      if (lm > M + CUT) {             // rare
        int row = n0 + rg*4 + r;
#pragma unroll
        for (int j = 0; j < 8; ++j) {
          if (l[j] > M + CUT) {
            int slot = atomicAdd(&cnt[row], 1);
            if (slot < SLOTS)
              cand[(size_t)row*SLOTS + slot] =
                  make_float2(l[j], __int_as_float(k0 + cg + 32*j));
          }
        }
      }
    }
    __syncthreads();
  }

  // reduce (m_thr, imin) across the 32 cg lanes
#pragma unroll
  for (int r = 0; r < 4; ++r) {
    float mm = m_thr[r];
    int   ii = imin[r];
    for (int off = 1; off < 32; off <<= 1) {
      float mo = __shfl_xor(mm, off);
      int   io = __shfl_xor(ii, off);
      ii = (mo > mm || (mo == mm && io < ii)) ? io : ii;
      mm = fmaxf(mm, mo);
    }
    if (cg == 0)
      part[(size_t)blockIdx.y*NROWS + n0 + rg*4 + r] = make_float2(mm, __int_as_float(ii));
  }
}

// ---------------------------------------------------------------------------
// combine: merge chunk maxima -> idx; softmax stats from candidates.
// NaN-proof: the argmax term (l == mm bit-exact) is added explicitly, and any
// candidate with code == argmin is skipped -> s >= 1, p <= 1 always.
// ---------------------------------------------------------------------------
__global__ __launch_bounds__(256) void combine_kernel(float* __restrict__ ws,
                                                      float* __restrict__ out) {
  const float2* part = (const float2*)(ws + WS_PART);
  const float2* cand = (const float2*)(ws + WS_CAND);
  const int*    cnt  = ((const int*)ws) + WS_CNT;

  int n = blockIdx.x*256 + threadIdx.x;
  float2 p0 = part[n];
  float mm = p0.x;
  int   ii = __float_as_int(p0.y);
#pragma unroll
  for (int c = 1; c < KSPLIT; ++c) {
    float2 pc = part[(size_t)c*NROWS + n];
    if (pc.x > mm) { mm = pc.x; ii = __float_as_int(pc.y); }  // ties keep earlier chunk
  }
  out[OUT_IDX + n] = (float)ii;

  int cn = cnt[n]; cn = cn < SLOTS ? cn : SLOTS;
  float s = 1.f;                       // argmax term: exp(mm - mm) == 1 exactly
  for (int i = 0; i < cn; ++i) {
    float2 cd = cand[(size_t)n*SLOTS + i];
    if (__float_as_int(cd.y) != ii) s += __expf(cd.x - mm);
  }
  float lse = mm + __logf(s);          // s >= 1 -> finite, lse >= mm

  float um   = mm - lse;               // <= 0
  float pmax = __expf(um);
  float plp  = pmax * um;
  atomicAdd(&ws[WS_AVGP + ii], pmax);
  for (int i = 0; i < cn; ++i) {
    float2 cd = cand[(size_t)n*SLOTS + i];
    if (__float_as_int(cd.y) == ii) continue;
    float u = cd.x - lse;              // <= 0
    float p = __expf(u);
    plp = fmaf(p, u, plp);
    atomicAdd(&ws[WS_AVGP + __float_as_int(cd.y)], p);
  }
  for (int off = 1; off < 64; off <<= 1) plp += __shfl_xor(plp, off);
  if ((threadIdx.x & 63) == 0) atomicAdd(&ws[WS_PLP], plp);
}

// ---------------------------------------------------------------------------
// zq epilogue: straight-through output + MSE
// ---------------------------------------------------------------------------
__global__ __launch_bounds__(256) void zq_kernel(const float* __restrict__ z,
                                                 const float* __restrict__ emb,
                                                 float* __restrict__ ws,
                                                 float* __restrict__ out) {
  int f  = blockIdx.x*256 + threadIdx.x;   // f = b*8192 + c*256 + hw
  int hw = f & 255;
  int c  = (f >> 8) & 31;
  int b  = f >> 13;
  int n  = b*256 + hw;
  int idx = (int)out[OUT_IDX + n];
  float zq = emb[(size_t)idx*CDIM + c];
  float zf = z[f];
  out[f] = zf + (zq - zf);
  float d = zq - zf;
  float msel = d*d;
  for (int off = 1; off < 64; off <<= 1) msel += __shfl_xor(msel, off);
  if ((threadIdx.x & 63) == 0) atomicAdd(&ws[WS_MSE], msel);
}

__global__ __launch_bounds__(256) void finalize_kernel(const float* __restrict__ ws,
                                                       float* __restrict__ out) {
  __shared__ float red[256];
  float h = 0.f;
  for (int k = threadIdx.x; k < KCODES; k += 256) {
    float ap = ws[WS_AVGP + k] * (1.f/8192.f);
    h += ap * __logf(ap + 1e-5f);
  }
  red[threadIdx.x] = h;
  __syncthreads();
  for (int st = 128; st > 0; st >>= 1) {
    if (threadIdx.x < st) red[threadIdx.x] += red[threadIdx.x + st];
    __syncthreads();
  }
  if (threadIdx.x == 0) {
    float mse        = ws[WS_MSE] * (1.f/(8192.f*32.f));
    float sample_ent = -ws[WS_PLP] * (1.f/8192.f);
    out[OUT_LOSS] = 1.25f*mse + 0.1f*(sample_ent + red[0]);
  }
}

extern "C" void kernel_launch(void* const* d_in, const int* in_sizes, int n_in,
                              void* d_out, int out_size, void* d_ws, size_t ws_size,
                              hipStream_t stream) {
  (void)in_sizes; (void)n_in; (void)out_size; (void)ws_size;
  const float* z   = (const float*)d_in[0];
  const float* emb = (const float*)d_in[1];
  float* out = (float*)d_out;
  float* ws  = (float*)d_ws;

  // zero scalars + avg_probs + candidate counters
  hipMemsetAsync(ws, 0, (size_t)(16 + KCODES + NROWS)*sizeof(float), stream);

  prep_kernel    <<<KCODES/256, 256, 0, stream>>>(emb, ws);
  pass1_part     <<<dim3(NROWS/RPB, KSPLIT), 256, 0, stream>>>(z, emb, ws);
  combine_kernel <<<NROWS/256, 256, 0, stream>>>(ws, out);
  zq_kernel      <<<(NROWS*CDIM)/256, 256, 0, stream>>>(z, emb, ws, out);
  finalize_kernel<<<1, 256, 0, stream>>>(ws, out);
}

// Round 7
// 525.010 us; speedup vs baseline: 10.0111x; 1.4725x over previous
//
#include <hip/hip_runtime.h>

#define KCODES 16384
#define CDIM   32
#define NROWS  8192
#define RPB    32                 // rows per block
#define KT     128                // codes per tile (double-buffered)
#define KSPLIT 4                  // K-chunks
#define CHUNK  (KCODES/KSPLIT)    // 4096
#define TILES  (CHUNK/KT)         // 32

// workspace layout (float indices)
#define WS_MSE   0
#define WS_PLP   1
#define WS_AVGP  16                    // [16384]
#define WS_ENORM (16 + KCODES)         // [16384]
#define WS_PART  (16 + 2*KCODES)       // float4[KSPLIT][NROWS][2]; byte off 131136 %16==0

// output layout (floats): z_q [0, N*C), loss [N*C], idx [N*C+1, ...)
#define OUT_LOSS (NROWS*CDIM)
#define OUT_IDX  (NROWS*CDIM + 1)

__global__ __launch_bounds__(256) void prep_kernel(const float* __restrict__ emb,
                                                   float* __restrict__ ws) {
  int k = blockIdx.x * 256 + threadIdx.x;
  const float4* p = (const float4*)(emb + (size_t)k * CDIM);
  float s = 0.f;
#pragma unroll
  for (int i = 0; i < 8; ++i) {
    float4 v = p[i];
    s += v.x*v.x + v.y*v.y + v.z*v.z + v.w*v.w;
  }
  ws[WS_ENORM + k] = s;
}

// ---------------------------------------------------------------------------
// pass1: block = (rowgroup, chunk). 32 rows x 4096 codes; thread = 4 rows x
// 4 codes, z held in registers (zreg), codebook tile double-buffered in LDS
// with one barrier per tile. Per-thread top-2 (l,code) in registers — no
// shuffles / atomics / exp in the hot loop (R6's 43.7M-conflict regression).
// NO min-waves __launch_bounds__: (256,3) spills accumulators (R3/R5, 9x).
// ---------------------------------------------------------------------------
__global__ __launch_bounds__(256) void pass1_part(const float* __restrict__ z,
                                                  const float* __restrict__ emb,
                                                  float* __restrict__ ws) {
  __shared__ float  zs[RPB][36];      // staging only; hoisted to regs after init
  __shared__ float  znorm_s[RPB];
  __shared__ float4 es4[2][KT][9];    // pad slot -> conflict-free b128 reads
  __shared__ float  es_n[2][KT];

  const int tid   = threadIdx.x;
  const int n0    = blockIdx.x * RPB;
  const int kbase = blockIdx.y * CHUNK;
  const int b     = n0 >> 8;
  const int hw0   = n0 & 255;

  float4* part = (float4*)(ws + WS_PART);

  { // stage z tile: 32 rows x 32 ch (coalesced)
    int c  = tid >> 3;
    int i0 = (tid & 7) * 4;
    const float4 v = *(const float4*)(z + (size_t)b*8192 + c*256 + hw0 + i0);
    zs[i0+0][c] = v.x; zs[i0+1][c] = v.y; zs[i0+2][c] = v.z; zs[i0+3][c] = v.w;
  }
  __syncthreads();
  if (tid < RPB) {
    float t = 0.f;
#pragma unroll
    for (int c = 0; c < CDIM; ++c) t += zs[tid][c]*zs[tid][c];
    znorm_s[tid] = t;
  }
  __syncthreads();

  const int rg = tid >> 5;            // rows rg*4 .. rg*4+3
  const int cg = tid & 31;            // codes cg + 32*j

  float zn[4];
  float4 zreg[4][8];                  // 128 VGPR: z rows in registers
#pragma unroll
  for (int r = 0; r < 4; ++r) {
    zn[r] = znorm_s[rg*4 + r];
#pragma unroll
    for (int c4 = 0; c4 < 8; ++c4)
      zreg[r][c4] = *(const float4*)(&zs[rg*4 + r][c4*4]);
  }

  float t1l[4], t2l[4];
  int   t1c[4], t2c[4];
#pragma unroll
  for (int r = 0; r < 4; ++r) { t1l[r] = -3.0e38f; t2l[r] = -3.0e38f; t1c[r] = kbase; t2c[r] = kbase; }

  const float4* emb4  = (const float4*)emb;
  const float*  enorm = ws + WS_ENORM;

  // prologue: stage tile 0 into buffer 0
  {
#pragma unroll
    for (int w = 0; w < 4; ++w) {
      int g = tid + 256*w;
      es4[0][g>>3][g&7] = emb4[(size_t)(kbase + (g>>3))*8 + (g&7)];
    }
    if (tid < KT) es_n[0][tid] = enorm[kbase + tid];
  }
  __syncthreads();

  for (int t = 0; t < TILES; ++t) {
    const int cur = t & 1, nxt = cur ^ 1;
    const int k0  = kbase + t*KT;

    // prefetch next tile to registers (loads in flight during FMAs)
    float4 gld[4]; float gn = 0.f;
    const bool more = (t + 1 < TILES);
    if (more) {
      const int k1 = k0 + KT;
#pragma unroll
      for (int w = 0; w < 4; ++w) {
        int g = tid + 256*w;
        gld[w] = emb4[(size_t)(k1 + (g>>3))*8 + (g&7)];
      }
      if (tid < KT) gn = enorm[k1 + tid];
    }

    float acc[4][4];
#pragma unroll
    for (int r = 0; r < 4; ++r)
#pragma unroll
      for (int j = 0; j < 4; ++j) acc[r][j] = 0.f;

#pragma unroll
    for (int c4 = 0; c4 < 8; ++c4) {
#pragma unroll
      for (int j = 0; j < 4; ++j) {
        float4 ev = es4[cur][cg + 32*j][c4];
#pragma unroll
        for (int r = 0; r < 4; ++r) {
          acc[r][j] = fmaf(zreg[r][c4].x, ev.x, acc[r][j]);
          acc[r][j] = fmaf(zreg[r][c4].y, ev.y, acc[r][j]);
          acc[r][j] = fmaf(zreg[r][c4].z, ev.z, acc[r][j]);
          acc[r][j] = fmaf(zreg[r][c4].w, ev.w, acc[r][j]);
        }
      }
    }

    float en[4];
#pragma unroll
    for (int j = 0; j < 4; ++j) en[j] = es_n[cur][cg + 32*j];

#pragma unroll
    for (int r = 0; r < 4; ++r) {
      float l[4];
#pragma unroll
      for (int j = 0; j < 4; ++j)
        l[j] = -100.f * fmaf(-2.f, acc[r][j], zn[r] + en[j]);   // same bits as R2/R6
      // branch-free sequential top-2 insert (codes ascending -> first-min ties)
#pragma unroll
      for (int j = 0; j < 4; ++j) {
        int   code = k0 + cg + 32*j;
        float lj   = l[j];
        bool  b1 = lj > t1l[r];
        bool  b2 = lj > t2l[r];
        float n2l = b1 ? t1l[r] : (b2 ? lj   : t2l[r]);
        int   n2c = b1 ? t1c[r] : (b2 ? code : t2c[r]);
        t1l[r] = b1 ? lj   : t1l[r];
        t1c[r] = b1 ? code : t1c[r];
        t2l[r] = n2l; t2c[r] = n2c;
      }
    }

    // write prefetched tile to the other buffer, single barrier per tile
    if (more) {
#pragma unroll
      for (int w = 0; w < 4; ++w) {
        int g = tid + 256*w;
        es4[nxt][g>>3][g&7] = gld[w];
      }
      if (tid < KT) es_n[nxt][tid] = gn;
    }
    __syncthreads();
  }

  // dump per-thread top-2 to LDS (reuse es4 space; loop's final barrier freed it)
  float2* dump = (float2*)&es4[0][0][0];   // 32 rows x 32 lanes x 2 = 16 KB
#pragma unroll
  for (int r = 0; r < 4; ++r) {
    int row = rg*4 + r;
    dump[(row*32 + cg)*2 + 0] = make_float2(t1l[r], __int_as_float(t1c[r]));
    dump[(row*32 + cg)*2 + 1] = make_float2(t2l[r], __int_as_float(t2c[r]));
  }
  __syncthreads();

  if (tid < RPB) {  // one thread per row: exact top-4 of 64 pairs
    float bl0=-3.0e38f, bl1=-3.0e38f, bl2=-3.0e38f, bl3=-3.0e38f;
    int   bc0=0, bc1=0, bc2=0, bc3=0;
    const float2* dp = dump + (size_t)tid*64;
    for (int i = 0; i < 64; ++i) {
      float2 pr = dp[i];
      float pl = pr.x; int pc = __float_as_int(pr.y);
      if (pl > bl0 || (pl == bl0 && pc < bc0)) {
        bl3=bl2; bc3=bc2; bl2=bl1; bc2=bc1; bl1=bl0; bc1=bc0; bl0=pl; bc0=pc;
      } else if (pl > bl1 || (pl == bl1 && pc < bc1)) {
        bl3=bl2; bc3=bc2; bl2=bl1; bc2=bc1; bl1=pl; bc1=pc;
      } else if (pl > bl2 || (pl == bl2 && pc < bc2)) {
        bl3=bl2; bc3=bc2; bl2=pl; bc2=pc;
      } else if (pl > bl3 || (pl == bl3 && pc < bc3)) {
        bl3=pl; bc3=pc;
      }
    }
    size_t o = ((size_t)blockIdx.y*NROWS + n0 + tid)*2;
    part[o+0] = make_float4(bl0, __int_as_float(bc0), bl1, __int_as_float(bc1));
    part[o+1] = make_float4(bl2, __int_as_float(bc2), bl3, __int_as_float(bc3));
  }
}

// ---------------------------------------------------------------------------
// combine: per row, 16 pairs (top-4 x 4 chunks) -> idx (exact), lse, plp,
// avg_probs atomics. Terms beyond the 16 are < e^-30 relative: invisible.
// S includes the max pair's exp(0)=1 -> s>=1, NaN-proof by construction.
// ---------------------------------------------------------------------------
__global__ __launch_bounds__(256) void combine_kernel(float* __restrict__ ws,
                                                      float* __restrict__ out) {
  const float4* part = (const float4*)(ws + WS_PART);
  int n = blockIdx.x*256 + threadIdx.x;

  float l[16]; int c[16];
#pragma unroll
  for (int ch = 0; ch < KSPLIT; ++ch) {
    float4 a = part[((size_t)ch*NROWS + n)*2 + 0];
    float4 d = part[((size_t)ch*NROWS + n)*2 + 1];
    l[ch*4+0] = a.x; c[ch*4+0] = __float_as_int(a.y);
    l[ch*4+1] = a.z; c[ch*4+1] = __float_as_int(a.w);
    l[ch*4+2] = d.x; c[ch*4+2] = __float_as_int(d.y);
    l[ch*4+3] = d.z; c[ch*4+3] = __float_as_int(d.w);
  }
  // global max; strict > keeps earliest chunk (lower codes) on exact ties;
  // within-chunk order already code-tie-broken in pass1.
  float mm = l[0]; int ii = c[0];
#pragma unroll
  for (int i = 1; i < 16; ++i)
    if (l[i] > mm) { mm = l[i]; ii = c[i]; }
  out[OUT_IDX + n] = (float)ii;

  float s = 0.f;
#pragma unroll
  for (int i = 0; i < 16; ++i) s += __expf(l[i] - mm);   // includes exp(0)=1
  float lse = mm + __logf(s);

  float plp = 0.f;
#pragma unroll
  for (int i = 0; i < 16; ++i) {
    float u = l[i] - lse;
    float p = __expf(u);
    plp = fmaf(p, u, plp);
    if (p > 1e-12f) atomicAdd(&ws[WS_AVGP + c[i]], p);
  }
  for (int off = 1; off < 64; off <<= 1) plp += __shfl_xor(plp, off);
  if ((threadIdx.x & 63) == 0) atomicAdd(&ws[WS_PLP], plp);
}

// ---------------------------------------------------------------------------
// zq epilogue: straight-through output + MSE
// ---------------------------------------------------------------------------
__global__ __launch_bounds__(256) void zq_kernel(const float* __restrict__ z,
                                                 const float* __restrict__ emb,
                                                 float* __restrict__ ws,
                                                 float* __restrict__ out) {
  int f  = blockIdx.x*256 + threadIdx.x;   // f = b*8192 + c*256 + hw
  int hw = f & 255;
  int c  = (f >> 8) & 31;
  int b  = f >> 13;
  int n  = b*256 + hw;
  int idx = (int)out[OUT_IDX + n];
  float zq = emb[(size_t)idx*CDIM + c];
  float zf = z[f];
  out[f] = zf + (zq - zf);
  float d = zq - zf;
  float msel = d*d;
  for (int off = 1; off < 64; off <<= 1) msel += __shfl_xor(msel, off);
  if ((threadIdx.x & 63) == 0) atomicAdd(&ws[WS_MSE], msel);
}

__global__ __launch_bounds__(256) void finalize_kernel(const float* __restrict__ ws,
                                                       float* __restrict__ out) {
  __shared__ float red[256];
  float h = 0.f;
  for (int k = threadIdx.x; k < KCODES; k += 256) {
    float ap = ws[WS_AVGP + k] * (1.f/8192.f);
    h += ap * __logf(ap + 1e-5f);
  }
  red[threadIdx.x] = h;
  __syncthreads();
  for (int st = 128; st > 0; st >>= 1) {
    if (threadIdx.x < st) red[threadIdx.x] += red[threadIdx.x + st];
    __syncthreads();
  }
  if (threadIdx.x == 0) {
    float mse        = ws[WS_MSE] * (1.f/(8192.f*32.f));
    float sample_ent = -ws[WS_PLP] * (1.f/8192.f);
    out[OUT_LOSS] = 1.25f*mse + 0.1f*(sample_ent + red[0]);
  }
}

extern "C" void kernel_launch(void* const* d_in, const int* in_sizes, int n_in,
                              void* d_out, int out_size, void* d_ws, size_t ws_size,
                              hipStream_t stream) {
  (void)in_sizes; (void)n_in; (void)out_size; (void)ws_size;
  const float* z   = (const float*)d_in[0];
  const float* emb = (const float*)d_in[1];
  float* out = (float*)d_out;
  float* ws  = (float*)d_ws;

  // zero scalar accumulators + avg_probs
  hipMemsetAsync(ws, 0, (size_t)(16 + KCODES)*sizeof(float), stream);

  prep_kernel    <<<KCODES/256, 256, 0, stream>>>(emb, ws);
  pass1_part     <<<dim3(NROWS/RPB, KSPLIT), 256, 0, stream>>>(z, emb, ws);
  combine_kernel <<<NROWS/256, 256, 0, stream>>>(ws, out);
  zq_kernel      <<<(NROWS*CDIM)/256, 256, 0, stream>>>(z, emb, ws, out);
  finalize_kernel<<<1, 256, 0, stream>>>(ws, out);
}